// Round 14
// baseline (88.324 us; speedup 1.0000x reference)
//
#include <hip/hip_runtime.h>

// Problem constants
#define B 32
#define S 2048
#define HDIM 1024
#define INV_SQRT_H 0.03125f     // 1/sqrt(1024)

// Workspace layout (float offsets). ~18 MB.
#define WS_Q    0                          // [B][H]        q = dec@Wq^T + bq
#define WS_QB   (32*1024)                  // [B] (+pad)    (q . bk) * INV_SQRT_H
#define WS_QWP  (WS_QB + 64)               // [8][B][H]     qW K-octant partials
#define WS_E    (WS_QWP + 8*32*1024)       // [B][S]        p = exp(energy)
#define WS_L    (WS_E + B*S)               // [B][128]      per-chunk l = sum p
#define WS_ACC  (WS_L + 32*128)            // [B*128][H]    per-chunk partial acc
#define WS_C    (WS_ACC + 32*128*1024)     // [B][H]        c_hat

__device__ __forceinline__ float dot4(float4 a, float4 b) {
    return a.x*b.x + a.y*b.y + a.z*b.z + a.w*b.w;
}

__device__ __forceinline__ float wave_reduce_add(float v) {
#pragma unroll
    for (int off = 32; off >= 1; off >>= 1) v += __shfl_xor(v, off);
    return v;
}

// ---------------------------------------------------------------------------
// P1: q[b,o], 4 batches/block (Wq traffic /4). grid 1024 = 8 bg * 128 oc.
__global__ __launch_bounds__(256) void k_q(const float* __restrict__ dec,
                                           const float* __restrict__ Wq,
                                           const float* __restrict__ bq,
                                           float* __restrict__ ws) {
    int bg = blockIdx.x >> 7;        // 0..7
    int oc = blockIdx.x & 127;       // 0..127
    int wave = threadIdx.x >> 6, lane = threadIdx.x & 63;
    int b0 = bg * 4;
    const float4* D = (const float4*)dec;
    float4 dv[4][4];
#pragma unroll
    for (int bb = 0; bb < 4; ++bb)
#pragma unroll
        for (int c = 0; c < 4; ++c)
            dv[bb][c] = D[(size_t)(b0 + bb) * 256 + c * 64 + lane];
#pragma unroll
    for (int i = 0; i < 2; ++i) {
        int o = oc * 8 + wave * 2 + i;
        const float4* w4 = (const float4*)(Wq + (size_t)o * HDIM);
        float4 a0 = w4[lane], a1 = w4[64+lane], a2 = w4[128+lane], a3 = w4[192+lane];
        float bqo = bq[o];
#pragma unroll
        for (int bb = 0; bb < 4; ++bb) {
            float d = dot4(a0, dv[bb][0]) + dot4(a1, dv[bb][1])
                    + dot4(a2, dv[bb][2]) + dot4(a3, dv[bb][3]);
            d = wave_reduce_add(d);
            if (lane == 0) ws[WS_Q + (b0 + bb) * HDIM + o] = d + bqo;
        }
    }
}

// ---------------------------------------------------------------------------
// P2 (R13 form): qW split-K octant partials, 2 batches/block.
// grid 2048 = 16 bg(2 b) * 16 hc * 8 qc.
__global__ __launch_bounds__(256) void k_qw(const float* __restrict__ Wk,
                                            const float* __restrict__ bk,
                                            float* __restrict__ ws) {
    __shared__ float lds[2][4][64];
    int bg = blockIdx.x >> 7;          // 0..15
    int hc = (blockIdx.x >> 3) & 15;   // 0..15
    int qc = blockIdx.x & 7;           // 0..7
    int t = threadIdx.x;
    int b0 = bg * 2;
    int col = hc * 64 + (t & 63);
    int os = t >> 6;                   // 0..3
    int o0 = qc * 128 + os * 32;
    const float* q0 = ws + WS_Q + b0 * HDIM;
    const float* q1 = q0 + HDIM;
    float acc0 = 0.f, acc1 = 0.f;
#pragma unroll 4
    for (int o = o0; o < o0 + 32; ++o) {
        float w = Wk[(size_t)o * HDIM + col];
        acc0 += q0[o] * w;
        acc1 += q1[o] * w;
    }
    lds[0][os][t & 63] = acc0;
    lds[1][os][t & 63] = acc1;
    __syncthreads();
    if (t < 128) {
        int bb = t >> 6, c = t & 63;
        ws[WS_QWP + (size_t)(qc * 32 + b0 + bb) * HDIM + hc * 64 + c]
            = lds[bb][0][c] + lds[bb][1][c] + lds[bb][2][c] + lds[bb][3][c];
    }
    if (hc == 0 && qc == 0 && t < 128) {
        int bb = t >> 6, l = t & 63;
        int b = b0 + bb;
        const float4* q4 = (const float4*)(ws + WS_Q + b * HDIM);
        const float4* bk4 = (const float4*)bk;
        float s2 = 0.f;
#pragma unroll
        for (int c = 0; c < 4; ++c) s2 += dot4(q4[64*c + l], bk4[64*c + l]);
        s2 = wave_reduce_add(s2);
        if (l == 0) ws[WS_QB + b] = s2 * INV_SQRT_H;
    }
}

// ---------------------------------------------------------------------------
// F1: flash over enc. grid 4096 = 32 b * 128 chunks of 16 rows; 4 rows/wave.
// (256,6) kept — VGPR cap 85 fits the ~76 natural allocation (no spill).
__global__ __launch_bounds__(256, 6) void k_flash(const float* __restrict__ enc,
                                                  float* __restrict__ ws) {
    __shared__ float lacc[4][HDIM];
    __shared__ float ll[4];
    int b = blockIdx.x >> 7;
    int ch = blockIdx.x & 127;
    int wave = threadIdx.x >> 6, lane = threadIdx.x & 63;

    // qW = sum of 8 split-K octant partials
    const float4* P4 = (const float4*)(ws + WS_QWP);
    float4 w[4];
#pragma unroll
    for (int c = 0; c < 4; ++c) {
        float4 s = {0.f, 0.f, 0.f, 0.f};
#pragma unroll
        for (int qp = 0; qp < 8; ++qp) {
            float4 p = P4[(size_t)(qp * 32 + b) * 256 + c * 64 + lane];
            s.x += p.x; s.y += p.y; s.z += p.z; s.w += p.w;
        }
        w[c] = s;
    }
    float qbs = ws[WS_QB + b];

    float l_run = 0.f;
    float4 A0 = {0,0,0,0}, A1 = A0, A2 = A0, A3 = A0;

    int s0 = ch * 16 + wave * 4;
    const float4* R = (const float4*)enc + (size_t)(b * S + s0) * 256;

#pragma unroll 2
    for (int i = 0; i < 4; ++i) {
        const float4* Ri = R + (size_t)i * 256;
        float4 e0 = Ri[lane], e1 = Ri[64+lane], e2 = Ri[128+lane], e3 = Ri[192+lane];
        float d = dot4(e0,w[0]) + dot4(e1,w[1]) + dot4(e2,w[2]) + dot4(e3,w[3]);
        d = wave_reduce_add(d);
        float p = __expf(d * INV_SQRT_H + qbs);
        if (lane == 0) ws[WS_E + b * S + s0 + i] = p;
        l_run += p;
        A0.x += p*e0.x; A0.y += p*e0.y; A0.z += p*e0.z; A0.w += p*e0.w;
        A1.x += p*e1.x; A1.y += p*e1.y; A1.z += p*e1.z; A1.w += p*e1.w;
        A2.x += p*e2.x; A2.y += p*e2.y; A2.z += p*e2.z; A2.w += p*e2.w;
        A3.x += p*e3.x; A3.y += p*e3.y; A3.z += p*e3.z; A3.w += p*e3.w;
    }

    // block combine over 4 waves
    float4* la4 = (float4*)lacc[wave];
    la4[lane] = A0; la4[64+lane] = A1; la4[128+lane] = A2; la4[192+lane] = A3;
    if (lane == 0) ll[wave] = l_run;
    __syncthreads();

    int t = threadIdx.x;
    float4 c0 = ((float4*)lacc[0])[t];
    float4 c1 = ((float4*)lacc[1])[t];
    float4 c2 = ((float4*)lacc[2])[t];
    float4 c3 = ((float4*)lacc[3])[t];
    float4 cc;
    cc.x = c0.x + c1.x + c2.x + c3.x;
    cc.y = c0.y + c1.y + c2.y + c3.y;
    cc.z = c0.z + c1.z + c2.z + c3.z;
    cc.w = c0.w + c1.w + c2.w + c3.w;
    ((float4*)(ws + WS_ACC))[(size_t)(b * 128 + ch) * 256 + t] = cc;
    if (t == 0) ws[WS_L + b * 128 + ch] = ll[0] + ll[1] + ll[2] + ll[3];
}

// ---------------------------------------------------------------------------
// F2: blocks 0..127: c_hat (4 h-slices/batch, 32 partials/thread + 4-way LDS
// tree). Blocks 128..383: attn = p/lg. lg reduce over 128 partials.
__global__ __launch_bounds__(256) void k_combine(float* __restrict__ ws,
                                                 float* __restrict__ out) {
    __shared__ float s_inv;
    int t = threadIdx.x;
    if (blockIdx.x < 128) {
        __shared__ float4 lred[4][64];
        int b  = blockIdx.x >> 2;     // 0..31
        int hs = blockIdx.x & 3;      // h-slice: 64 float4 each
        if (t < 64) {
            float li = ws[WS_L + b * 128 + t] + ws[WS_L + b * 128 + 64 + t];
            float lg = wave_reduce_add(li);
            if (t == 0) s_inv = 1.f / lg;
        }
        __syncthreads();
        int ig = t >> 6;              // partial-group 0..3 (32 partials each)
        int h4 = hs * 64 + (t & 63);  // float4 column
        const float4* acc4 = ((const float4*)(ws + WS_ACC)) + (size_t)b * 128 * 256;
        float4 c = {0, 0, 0, 0};
#pragma unroll
        for (int ip = ig * 32; ip < ig * 32 + 32; ++ip) {
            float4 a = acc4[(size_t)ip * 256 + h4];
            c.x += a.x; c.y += a.y; c.z += a.z; c.w += a.w;
        }
        lred[ig][t & 63] = c;
        __syncthreads();
        if (t < 64) {
            float4 r0 = lred[0][t], r1 = lred[1][t], r2 = lred[2][t], r3 = lred[3][t];
            float inv = s_inv;
            float4 cc;
            cc.x = (r0.x + r1.x + r2.x + r3.x) * inv;
            cc.y = (r0.y + r1.y + r2.y + r3.y) * inv;
            cc.z = (r0.z + r1.z + r2.z + r3.z) * inv;
            cc.w = (r0.w + r1.w + r2.w + r3.w) * inv;
            ((float4*)(ws + WS_C))[b * 256 + hs * 64 + t] = cc;
        }
    } else {
        int gt = (blockIdx.x - 128) * 256 + t;    // b*S + s
        int b = gt >> 11;
        if (t < 64) {
            float li = ws[WS_L + b * 128 + t] + ws[WS_L + b * 128 + 64 + t];
            float lg = wave_reduce_add(li);
            if (t == 0) s_inv = 1.f / lg;
        }
        __syncthreads();
        out[B * HDIM + gt] = ws[WS_E + gt] * s_inv;
    }
}

// ---------------------------------------------------------------------------
// F3: context GEMV + DyT, 4 batches/block (Wv traffic /4). grid 1024.
__global__ __launch_bounds__(256) void k_out(const float* __restrict__ Wv,
                                             const float* __restrict__ bv,
                                             const float* __restrict__ alpha,
                                             const float* __restrict__ gamma,
                                             const float* __restrict__ beta,
                                             const float* __restrict__ ws,
                                             float* __restrict__ out) {
    int bg = blockIdx.x >> 7;        // 0..7
    int oc = blockIdx.x & 127;       // 0..127
    int wave = threadIdx.x >> 6, lane = threadIdx.x & 63;
    int b0 = bg * 4;
    const float4* C4 = (const float4*)(ws + WS_C);
    float4 dv[4][4];
#pragma unroll
    for (int bb = 0; bb < 4; ++bb)
#pragma unroll
        for (int c = 0; c < 4; ++c)
            dv[bb][c] = C4[(size_t)(b0 + bb) * 256 + c * 64 + lane];
    float al = alpha[0];
#pragma unroll
    for (int i = 0; i < 2; ++i) {
        int o = oc * 8 + wave * 2 + i;
        const float4* w4 = (const float4*)(Wv + (size_t)o * HDIM);
        float4 a0 = w4[lane], a1 = w4[64+lane], a2 = w4[128+lane], a3 = w4[192+lane];
        float bvo = bv[o], gm = gamma[o], bt = beta[o];
#pragma unroll
        for (int bb = 0; bb < 4; ++bb) {
            float d = dot4(a0, dv[bb][0]) + dot4(a1, dv[bb][1])
                    + dot4(a2, dv[bb][2]) + dot4(a3, dv[bb][3]);
            d = wave_reduce_add(d);
            if (lane == 0) {
                float y = d + bvo;
                out[(b0 + bb) * HDIM + o] = gm * tanhf(al * y) + bt;
            }
        }
    }
}

// ---------------------------------------------------------------------------
extern "C" void kernel_launch(void* const* d_in, const int* in_sizes, int n_in,
                              void* d_out, int out_size, void* d_ws, size_t ws_size,
                              hipStream_t stream) {
    const float* dec   = (const float*)d_in[0];
    const float* enc   = (const float*)d_in[1];
    const float* Wq    = (const float*)d_in[2];
    const float* bq    = (const float*)d_in[3];
    const float* Wk    = (const float*)d_in[4];
    const float* bk    = (const float*)d_in[5];
    const float* Wv    = (const float*)d_in[6];
    const float* bv    = (const float*)d_in[7];
    const float* alpha = (const float*)d_in[8];
    const float* gamma = (const float*)d_in[9];
    const float* beta  = (const float*)d_in[10];
    float* out = (float*)d_out;
    float* ws  = (float*)d_ws;

    hipLaunchKernelGGL(k_q,       dim3(1024), dim3(256), 0, stream, dec, Wq, bq, ws);
    hipLaunchKernelGGL(k_qw,      dim3(2048), dim3(256), 0, stream, Wk, bk, ws);
    hipLaunchKernelGGL(k_flash,   dim3(4096), dim3(256), 0, stream, enc, ws);
    hipLaunchKernelGGL(k_combine, dim3(384),  dim3(256), 0, stream, ws, out);
    hipLaunchKernelGGL(k_out,     dim3(1024), dim3(256), 0, stream, Wv, bv, alpha, gamma, beta, ws, out);
}

// Round 15
// 77.799 us; speedup vs baseline: 1.1353x; 1.1353x over previous
//
#include <hip/hip_runtime.h>

// Problem constants
#define B 32
#define S 2048
#define HDIM 1024
#define INV_SQRT_H 0.03125f     // 1/sqrt(1024)

// Workspace layout (float offsets). ~9.8 MB.
#define WS_Q    0                          // [B][H]        q = dec@Wq^T + bq
#define WS_QB   (32*1024)                  // [B] (+pad)    (q . bk) * INV_SQRT_H
#define WS_QWP  (WS_QB + 64)               // [8][B][H]     qW K-octant partials
#define WS_E    (WS_QWP + 8*32*1024)       // [B][S]        p = exp(energy)
#define WS_L    (WS_E + B*S)               // [B][64]       per-chunk l = sum p
#define WS_ACC  (WS_L + 32*64)             // [B*64][H]     per-chunk partial acc
#define WS_C    (WS_ACC + 32*64*1024)      // [B][H]        c_hat

__device__ __forceinline__ float dot4(float4 a, float4 b) {
    return a.x*b.x + a.y*b.y + a.z*b.z + a.w*b.w;
}

__device__ __forceinline__ float wave_reduce_add(float v) {
#pragma unroll
    for (int off = 32; off >= 1; off >>= 1) v += __shfl_xor(v, off);
    return v;
}

// ---------------------------------------------------------------------------
// P1: q[b,o], 4 batches/block (Wq traffic /4). grid 1024 = 8 bg * 128 oc.
__global__ __launch_bounds__(256) void k_q(const float* __restrict__ dec,
                                           const float* __restrict__ Wq,
                                           const float* __restrict__ bq,
                                           float* __restrict__ ws) {
    int bg = blockIdx.x >> 7;        // 0..7
    int oc = blockIdx.x & 127;       // 0..127
    int wave = threadIdx.x >> 6, lane = threadIdx.x & 63;
    int b0 = bg * 4;
    const float4* D = (const float4*)dec;
    float4 dv[4][4];
#pragma unroll
    for (int bb = 0; bb < 4; ++bb)
#pragma unroll
        for (int c = 0; c < 4; ++c)
            dv[bb][c] = D[(size_t)(b0 + bb) * 256 + c * 64 + lane];
#pragma unroll
    for (int i = 0; i < 2; ++i) {
        int o = oc * 8 + wave * 2 + i;
        const float4* w4 = (const float4*)(Wq + (size_t)o * HDIM);
        float4 a0 = w4[lane], a1 = w4[64+lane], a2 = w4[128+lane], a3 = w4[192+lane];
        float bqo = bq[o];
#pragma unroll
        for (int bb = 0; bb < 4; ++bb) {
            float d = dot4(a0, dv[bb][0]) + dot4(a1, dv[bb][1])
                    + dot4(a2, dv[bb][2]) + dot4(a3, dv[bb][3]);
            d = wave_reduce_add(d);
            if (lane == 0) ws[WS_Q + (b0 + bb) * HDIM + o] = d + bqo;
        }
    }
}

// ---------------------------------------------------------------------------
// P2 (R13 form): qW split-K octant partials, 2 batches/block.
// grid 2048 = 16 bg(2 b) * 16 hc * 8 qc.
__global__ __launch_bounds__(256) void k_qw(const float* __restrict__ Wk,
                                            const float* __restrict__ bk,
                                            float* __restrict__ ws) {
    __shared__ float lds[2][4][64];
    int bg = blockIdx.x >> 7;          // 0..15
    int hc = (blockIdx.x >> 3) & 15;   // 0..15
    int qc = blockIdx.x & 7;           // 0..7
    int t = threadIdx.x;
    int b0 = bg * 2;
    int col = hc * 64 + (t & 63);
    int os = t >> 6;                   // 0..3
    int o0 = qc * 128 + os * 32;
    const float* q0 = ws + WS_Q + b0 * HDIM;
    const float* q1 = q0 + HDIM;
    float acc0 = 0.f, acc1 = 0.f;
#pragma unroll 4
    for (int o = o0; o < o0 + 32; ++o) {
        float w = Wk[(size_t)o * HDIM + col];
        acc0 += q0[o] * w;
        acc1 += q1[o] * w;
    }
    lds[0][os][t & 63] = acc0;
    lds[1][os][t & 63] = acc1;
    __syncthreads();
    if (t < 128) {
        int bb = t >> 6, c = t & 63;
        ws[WS_QWP + (size_t)(qc * 32 + b0 + bb) * HDIM + hc * 64 + c]
            = lds[bb][0][c] + lds[bb][1][c] + lds[bb][2][c] + lds[bb][3][c];
    }
    if (hc == 0 && qc == 0 && t < 128) {
        int bb = t >> 6, l = t & 63;
        int b = b0 + bb;
        const float4* q4 = (const float4*)(ws + WS_Q + b * HDIM);
        const float4* bk4 = (const float4*)bk;
        float s2 = 0.f;
#pragma unroll
        for (int c = 0; c < 4; ++c) s2 += dot4(q4[64*c + l], bk4[64*c + l]);
        s2 = wave_reduce_add(s2);
        if (l == 0) ws[WS_QB + b] = s2 * INV_SQRT_H;
    }
}

// ---------------------------------------------------------------------------
// F1: flash over enc. grid 2048 = 32 b * 64 chunks of 32 rows; (256,6).
// Prologue: qW octant-reduction staged through LDS once per block
// (global prologue traffic /4 vs per-wave reads: 128 KB -> 32 KB per block).
__global__ __launch_bounds__(256, 6) void k_flash(const float* __restrict__ enc,
                                                  float* __restrict__ ws) {
    __shared__ float lacc[4][HDIM];
    __shared__ float ll[4];
    int b = blockIdx.x >> 6;
    int ch = blockIdx.x & 63;
    int wave = threadIdx.x >> 6, lane = threadIdx.x & 63;
    int t = threadIdx.x;

    // Stage 1: each thread reduces 8 octants for its float4-column -> LDS
    {
        const float4* P4 = (const float4*)(ws + WS_QWP);
        float4 s = {0.f, 0.f, 0.f, 0.f};
#pragma unroll
        for (int qp = 0; qp < 8; ++qp) {
            float4 p = P4[(size_t)(qp * 32 + b) * 256 + t];
            s.x += p.x; s.y += p.y; s.z += p.z; s.w += p.w;
        }
        ((float4*)lacc)[t] = s;      // reuse lacc's first 4 KB as qw staging
    }
    __syncthreads();
    float4 w[4];
#pragma unroll
    for (int c = 0; c < 4; ++c) w[c] = ((float4*)lacc)[c * 64 + lane];
    __syncthreads();                 // all reads done before lacc reuse below
    float qbs = ws[WS_QB + b];

    float l_run = 0.f;
    float4 A0 = {0,0,0,0}, A1 = A0, A2 = A0, A3 = A0;

    int s0 = ch * 32 + wave * 8;
    const float4* R = (const float4*)enc + (size_t)(b * S + s0) * 256;

#pragma unroll 2
    for (int i = 0; i < 8; ++i) {
        const float4* Ri = R + (size_t)i * 256;
        float4 e0 = Ri[lane], e1 = Ri[64+lane], e2 = Ri[128+lane], e3 = Ri[192+lane];
        float d = dot4(e0,w[0]) + dot4(e1,w[1]) + dot4(e2,w[2]) + dot4(e3,w[3]);
        d = wave_reduce_add(d);
        float p = __expf(d * INV_SQRT_H + qbs);
        if (lane == 0) ws[WS_E + b * S + s0 + i] = p;
        l_run += p;
        A0.x += p*e0.x; A0.y += p*e0.y; A0.z += p*e0.z; A0.w += p*e0.w;
        A1.x += p*e1.x; A1.y += p*e1.y; A1.z += p*e1.z; A1.w += p*e1.w;
        A2.x += p*e2.x; A2.y += p*e2.y; A2.z += p*e2.z; A2.w += p*e2.w;
        A3.x += p*e3.x; A3.y += p*e3.y; A3.z += p*e3.z; A3.w += p*e3.w;
    }

    // block combine over 4 waves
    float4* la4 = (float4*)lacc[wave];
    la4[lane] = A0; la4[64+lane] = A1; la4[128+lane] = A2; la4[192+lane] = A3;
    if (lane == 0) ll[wave] = l_run;
    __syncthreads();

    float4 c0 = ((float4*)lacc[0])[t];
    float4 c1 = ((float4*)lacc[1])[t];
    float4 c2 = ((float4*)lacc[2])[t];
    float4 c3 = ((float4*)lacc[3])[t];
    float4 cc;
    cc.x = c0.x + c1.x + c2.x + c3.x;
    cc.y = c0.y + c1.y + c2.y + c3.y;
    cc.z = c0.z + c1.z + c2.z + c3.z;
    cc.w = c0.w + c1.w + c2.w + c3.w;
    ((float4*)(ws + WS_ACC))[(size_t)(b * 64 + ch) * 256 + t] = cc;
    if (t == 0) ws[WS_L + b * 64 + ch] = ll[0] + ll[1] + ll[2] + ll[3];
}

// ---------------------------------------------------------------------------
// F2 (R12 form): blocks 0..127: c_hat (4 h-slices/batch); 128..383: attn out.
__global__ __launch_bounds__(256) void k_combine(float* __restrict__ ws,
                                                 float* __restrict__ out) {
    __shared__ float s_inv;
    int t = threadIdx.x;
    if (blockIdx.x < 128) {
        __shared__ float4 lred[4][64];
        int b  = blockIdx.x >> 2;     // 0..31
        int hs = blockIdx.x & 3;      // h-slice: 64 float4 each
        if (t < 64) {
            float li = ws[WS_L + b * 64 + t];
            float lg = wave_reduce_add(li);
            if (t == 0) s_inv = 1.f / lg;
        }
        __syncthreads();
        int ig = t >> 6;              // partial-group 0..3
        int h4 = hs * 64 + (t & 63);  // float4 column
        const float4* acc4 = ((const float4*)(ws + WS_ACC)) + (size_t)b * 64 * 256;
        float4 c = {0, 0, 0, 0};
#pragma unroll
        for (int ip = ig * 16; ip < ig * 16 + 16; ++ip) {
            float4 a = acc4[(size_t)ip * 256 + h4];
            c.x += a.x; c.y += a.y; c.z += a.z; c.w += a.w;
        }
        lred[ig][t & 63] = c;
        __syncthreads();
        if (t < 64) {
            float4 r0 = lred[0][t], r1 = lred[1][t], r2 = lred[2][t], r3 = lred[3][t];
            float inv = s_inv;
            float4 cc;
            cc.x = (r0.x + r1.x + r2.x + r3.x) * inv;
            cc.y = (r0.y + r1.y + r2.y + r3.y) * inv;
            cc.z = (r0.z + r1.z + r2.z + r3.z) * inv;
            cc.w = (r0.w + r1.w + r2.w + r3.w) * inv;
            ((float4*)(ws + WS_C))[b * 256 + hs * 64 + t] = cc;
        }
    } else {
        int gt = (blockIdx.x - 128) * 256 + t;    // b*S + s
        int b = gt >> 11;
        if (t < 64) {
            float li = ws[WS_L + b * 64 + t];
            float lg = wave_reduce_add(li);
            if (t == 0) s_inv = 1.f / lg;
        }
        __syncthreads();
        out[B * HDIM + gt] = ws[WS_E + gt] * s_inv;
    }
}

// ---------------------------------------------------------------------------
// F3: context GEMV + DyT, 4 batches/block (Wv traffic /4). grid 1024.
__global__ __launch_bounds__(256) void k_out(const float* __restrict__ Wv,
                                             const float* __restrict__ bv,
                                             const float* __restrict__ alpha,
                                             const float* __restrict__ gamma,
                                             const float* __restrict__ beta,
                                             const float* __restrict__ ws,
                                             float* __restrict__ out) {
    int bg = blockIdx.x >> 7;        // 0..7
    int oc = blockIdx.x & 127;       // 0..127
    int wave = threadIdx.x >> 6, lane = threadIdx.x & 63;
    int b0 = bg * 4;
    const float4* C4 = (const float4*)(ws + WS_C);
    float4 dv[4][4];
#pragma unroll
    for (int bb = 0; bb < 4; ++bb)
#pragma unroll
        for (int c = 0; c < 4; ++c)
            dv[bb][c] = C4[(size_t)(b0 + bb) * 256 + c * 64 + lane];
    float al = alpha[0];
#pragma unroll
    for (int i = 0; i < 2; ++i) {
        int o = oc * 8 + wave * 2 + i;
        const float4* w4 = (const float4*)(Wv + (size_t)o * HDIM);
        float4 a0 = w4[lane], a1 = w4[64+lane], a2 = w4[128+lane], a3 = w4[192+lane];
        float bvo = bv[o], gm = gamma[o], bt = beta[o];
#pragma unroll
        for (int bb = 0; bb < 4; ++bb) {
            float d = dot4(a0, dv[bb][0]) + dot4(a1, dv[bb][1])
                    + dot4(a2, dv[bb][2]) + dot4(a3, dv[bb][3]);
            d = wave_reduce_add(d);
            if (lane == 0) {
                float y = d + bvo;
                out[(b0 + bb) * HDIM + o] = gm * tanhf(al * y) + bt;
            }
        }
    }
}

// ---------------------------------------------------------------------------
extern "C" void kernel_launch(void* const* d_in, const int* in_sizes, int n_in,
                              void* d_out, int out_size, void* d_ws, size_t ws_size,
                              hipStream_t stream) {
    const float* dec   = (const float*)d_in[0];
    const float* enc   = (const float*)d_in[1];
    const float* Wq    = (const float*)d_in[2];
    const float* bq    = (const float*)d_in[3];
    const float* Wk    = (const float*)d_in[4];
    const float* bk    = (const float*)d_in[5];
    const float* Wv    = (const float*)d_in[6];
    const float* bv    = (const float*)d_in[7];
    const float* alpha = (const float*)d_in[8];
    const float* gamma = (const float*)d_in[9];
    const float* beta  = (const float*)d_in[10];
    float* out = (float*)d_out;
    float* ws  = (float*)d_ws;

    hipLaunchKernelGGL(k_q,       dim3(1024), dim3(256), 0, stream, dec, Wq, bq, ws);
    hipLaunchKernelGGL(k_qw,      dim3(2048), dim3(256), 0, stream, Wk, bk, ws);
    hipLaunchKernelGGL(k_flash,   dim3(2048), dim3(256), 0, stream, enc, ws);
    hipLaunchKernelGGL(k_combine, dim3(384),  dim3(256), 0, stream, ws, out);
    hipLaunchKernelGGL(k_out,     dim3(1024), dim3(256), 0, stream, Wv, bv, alpha, gamma, beta, ws, out);
}

// Round 16
// 75.938 us; speedup vs baseline: 1.1631x; 1.0245x over previous
//
#include <hip/hip_runtime.h>

// Problem constants
#define B 32
#define S 2048
#define HDIM 1024
#define INV_SQRT_H 0.03125f     // 1/sqrt(1024)

// Workspace layout (float offsets). ~9.8 MB.
#define WS_Q    0                          // [B][H]        q = dec@Wq^T + bq
#define WS_QB   (32*1024)                  // [B] (+pad)    (q . bk) * INV_SQRT_H
#define WS_QWP  (WS_QB + 64)               // [8][B][H]     qW K-octant partials
#define WS_E    (WS_QWP + 8*32*1024)       // [B][S]        p = exp(energy)
#define WS_L    (WS_E + B*S)               // [B][64]       per-chunk l = sum p
#define WS_ACC  (WS_L + 32*64)             // [B*64][H]     per-chunk partial acc
#define WS_C    (WS_ACC + 32*64*1024)      // [B][H]        c_hat

__device__ __forceinline__ float dot4(float4 a, float4 b) {
    return a.x*b.x + a.y*b.y + a.z*b.z + a.w*b.w;
}

__device__ __forceinline__ float wave_reduce_add(float v) {
#pragma unroll
    for (int off = 32; off >= 1; off >>= 1) v += __shfl_xor(v, off);
    return v;
}

// ---------------------------------------------------------------------------
// P1: q[b,o], 4 batches/block (Wq traffic /4). grid 1024 = 8 bg * 128 oc.
__global__ __launch_bounds__(256) void k_q(const float* __restrict__ dec,
                                           const float* __restrict__ Wq,
                                           const float* __restrict__ bq,
                                           float* __restrict__ ws) {
    int bg = blockIdx.x >> 7;        // 0..7
    int oc = blockIdx.x & 127;       // 0..127
    int wave = threadIdx.x >> 6, lane = threadIdx.x & 63;
    int b0 = bg * 4;
    const float4* D = (const float4*)dec;
    float4 dv[4][4];
#pragma unroll
    for (int bb = 0; bb < 4; ++bb)
#pragma unroll
        for (int c = 0; c < 4; ++c)
            dv[bb][c] = D[(size_t)(b0 + bb) * 256 + c * 64 + lane];
#pragma unroll
    for (int i = 0; i < 2; ++i) {
        int o = oc * 8 + wave * 2 + i;
        const float4* w4 = (const float4*)(Wq + (size_t)o * HDIM);
        float4 a0 = w4[lane], a1 = w4[64+lane], a2 = w4[128+lane], a3 = w4[192+lane];
        float bqo = bq[o];
#pragma unroll
        for (int bb = 0; bb < 4; ++bb) {
            float d = dot4(a0, dv[bb][0]) + dot4(a1, dv[bb][1])
                    + dot4(a2, dv[bb][2]) + dot4(a3, dv[bb][3]);
            d = wave_reduce_add(d);
            if (lane == 0) ws[WS_Q + (b0 + bb) * HDIM + o] = d + bqo;
        }
    }
}

// ---------------------------------------------------------------------------
// P2: qW split-K octant partials, 2 batches/block (Wk traffic 128->64 MB,
// concurrency kept at 2048). grid 2048 = 16 bg(2 b) * 16 hc * 8 qc.
__global__ __launch_bounds__(256) void k_qw(const float* __restrict__ Wk,
                                            const float* __restrict__ bk,
                                            float* __restrict__ ws) {
    __shared__ float lds[2][4][64];
    int bg = blockIdx.x >> 7;          // 0..15
    int hc = (blockIdx.x >> 3) & 15;   // 0..15
    int qc = blockIdx.x & 7;           // 0..7
    int t = threadIdx.x;
    int b0 = bg * 2;
    int col = hc * 64 + (t & 63);
    int os = t >> 6;                   // 0..3
    int o0 = qc * 128 + os * 32;
    const float* q0 = ws + WS_Q + b0 * HDIM;
    const float* q1 = q0 + HDIM;
    float acc0 = 0.f, acc1 = 0.f;
#pragma unroll 4
    for (int o = o0; o < o0 + 32; ++o) {
        float w = Wk[(size_t)o * HDIM + col];
        acc0 += q0[o] * w;
        acc1 += q1[o] * w;
    }
    lds[0][os][t & 63] = acc0;
    lds[1][os][t & 63] = acc1;
    __syncthreads();
    if (t < 128) {
        int bb = t >> 6, c = t & 63;
        ws[WS_QWP + (size_t)(qc * 32 + b0 + bb) * HDIM + hc * 64 + c]
            = lds[bb][0][c] + lds[bb][1][c] + lds[bb][2][c] + lds[bb][3][c];
    }
    if (hc == 0 && qc == 0 && t < 128) {
        int bb = t >> 6, l = t & 63;
        int b = b0 + bb;
        const float4* q4 = (const float4*)(ws + WS_Q + b * HDIM);
        const float4* bk4 = (const float4*)bk;
        float s2 = 0.f;
#pragma unroll
        for (int c = 0; c < 4; ++c) s2 += dot4(q4[64*c + l], bk4[64*c + l]);
        s2 = wave_reduce_add(s2);
        if (l == 0) ws[WS_QB + b] = s2 * INV_SQRT_H;
    }
}

// ---------------------------------------------------------------------------
// F1: flash over enc. grid 2048 = 32 b * 64 chunks of 32 rows; (256,6).
__global__ __launch_bounds__(256, 6) void k_flash(const float* __restrict__ enc,
                                                  float* __restrict__ ws) {
    __shared__ float lacc[4][HDIM];
    __shared__ float ll[4];
    int b = blockIdx.x >> 6;
    int ch = blockIdx.x & 63;
    int wave = threadIdx.x >> 6, lane = threadIdx.x & 63;

    // qW = sum of 8 split-K octant partials
    const float4* P4 = (const float4*)(ws + WS_QWP);
    float4 w[4];
#pragma unroll
    for (int c = 0; c < 4; ++c) {
        float4 s = {0.f, 0.f, 0.f, 0.f};
#pragma unroll
        for (int qp = 0; qp < 8; ++qp) {
            float4 p = P4[(size_t)(qp * 32 + b) * 256 + c * 64 + lane];
            s.x += p.x; s.y += p.y; s.z += p.z; s.w += p.w;
        }
        w[c] = s;
    }
    float qbs = ws[WS_QB + b];

    float l_run = 0.f;
    float4 A0 = {0,0,0,0}, A1 = A0, A2 = A0, A3 = A0;

    int s0 = ch * 32 + wave * 8;
    const float4* R = (const float4*)enc + (size_t)(b * S + s0) * 256;

#pragma unroll 2
    for (int i = 0; i < 8; ++i) {
        const float4* Ri = R + (size_t)i * 256;
        float4 e0 = Ri[lane], e1 = Ri[64+lane], e2 = Ri[128+lane], e3 = Ri[192+lane];
        float d = dot4(e0,w[0]) + dot4(e1,w[1]) + dot4(e2,w[2]) + dot4(e3,w[3]);
        d = wave_reduce_add(d);
        float p = __expf(d * INV_SQRT_H + qbs);
        if (lane == 0) ws[WS_E + b * S + s0 + i] = p;
        l_run += p;
        A0.x += p*e0.x; A0.y += p*e0.y; A0.z += p*e0.z; A0.w += p*e0.w;
        A1.x += p*e1.x; A1.y += p*e1.y; A1.z += p*e1.z; A1.w += p*e1.w;
        A2.x += p*e2.x; A2.y += p*e2.y; A2.z += p*e2.z; A2.w += p*e2.w;
        A3.x += p*e3.x; A3.y += p*e3.y; A3.z += p*e3.z; A3.w += p*e3.w;
    }

    // block combine over 4 waves
    float4* la4 = (float4*)lacc[wave];
    la4[lane] = A0; la4[64+lane] = A1; la4[128+lane] = A2; la4[192+lane] = A3;
    if (lane == 0) ll[wave] = l_run;
    __syncthreads();

    int t = threadIdx.x;
    float4 c0 = ((float4*)lacc[0])[t];
    float4 c1 = ((float4*)lacc[1])[t];
    float4 c2 = ((float4*)lacc[2])[t];
    float4 c3 = ((float4*)lacc[3])[t];
    float4 cc;
    cc.x = c0.x + c1.x + c2.x + c3.x;
    cc.y = c0.y + c1.y + c2.y + c3.y;
    cc.z = c0.z + c1.z + c2.z + c3.z;
    cc.w = c0.w + c1.w + c2.w + c3.w;
    ((float4*)(ws + WS_ACC))[(size_t)(b * 64 + ch) * 256 + t] = cc;
    if (t == 0) ws[WS_L + b * 64 + ch] = ll[0] + ll[1] + ll[2] + ll[3];
}

// ---------------------------------------------------------------------------
// F2: blocks 0..127: c_hat (4 h-slices/batch, 16 partials/thread + 4-way LDS
// tree). Blocks 128..383: attn = p/lg.
__global__ __launch_bounds__(256) void k_combine(float* __restrict__ ws,
                                                 float* __restrict__ out) {
    __shared__ float s_inv;
    int t = threadIdx.x;
    if (blockIdx.x < 128) {
        __shared__ float4 lred[4][64];
        int b  = blockIdx.x >> 2;     // 0..31
        int hs = blockIdx.x & 3;      // h-slice: 64 float4 each
        if (t < 64) {
            float li = ws[WS_L + b * 64 + t];
            float lg = wave_reduce_add(li);
            if (t == 0) s_inv = 1.f / lg;
        }
        __syncthreads();
        int ig = t >> 6;              // partial-group 0..3
        int h4 = hs * 64 + (t & 63);  // float4 column
        const float4* acc4 = ((const float4*)(ws + WS_ACC)) + (size_t)b * 64 * 256;
        float4 c = {0, 0, 0, 0};
#pragma unroll
        for (int ip = ig * 16; ip < ig * 16 + 16; ++ip) {
            float4 a = acc4[(size_t)ip * 256 + h4];
            c.x += a.x; c.y += a.y; c.z += a.z; c.w += a.w;
        }
        lred[ig][t & 63] = c;
        __syncthreads();
        if (t < 64) {
            float4 r0 = lred[0][t], r1 = lred[1][t], r2 = lred[2][t], r3 = lred[3][t];
            float inv = s_inv;
            float4 cc;
            cc.x = (r0.x + r1.x + r2.x + r3.x) * inv;
            cc.y = (r0.y + r1.y + r2.y + r3.y) * inv;
            cc.z = (r0.z + r1.z + r2.z + r3.z) * inv;
            cc.w = (r0.w + r1.w + r2.w + r3.w) * inv;
            ((float4*)(ws + WS_C))[b * 256 + hs * 64 + t] = cc;
        }
    } else {
        int gt = (blockIdx.x - 128) * 256 + t;    // b*S + s
        int b = gt >> 11;
        if (t < 64) {
            float li = ws[WS_L + b * 64 + t];
            float lg = wave_reduce_add(li);
            if (t == 0) s_inv = 1.f / lg;
        }
        __syncthreads();
        out[B * HDIM + gt] = ws[WS_E + gt] * s_inv;
    }
}

// ---------------------------------------------------------------------------
// F3: context GEMV + DyT, 4 batches/block (Wv traffic /4). grid 1024.
__global__ __launch_bounds__(256) void k_out(const float* __restrict__ Wv,
                                             const float* __restrict__ bv,
                                             const float* __restrict__ alpha,
                                             const float* __restrict__ gamma,
                                             const float* __restrict__ beta,
                                             const float* __restrict__ ws,
                                             float* __restrict__ out) {
    int bg = blockIdx.x >> 7;        // 0..7
    int oc = blockIdx.x & 127;       // 0..127
    int wave = threadIdx.x >> 6, lane = threadIdx.x & 63;
    int b0 = bg * 4;
    const float4* C4 = (const float4*)(ws + WS_C);
    float4 dv[4][4];
#pragma unroll
    for (int bb = 0; bb < 4; ++bb)
#pragma unroll
        for (int c = 0; c < 4; ++c)
            dv[bb][c] = C4[(size_t)(b0 + bb) * 256 + c * 64 + lane];
    float al = alpha[0];
#pragma unroll
    for (int i = 0; i < 2; ++i) {
        int o = oc * 8 + wave * 2 + i;
        const float4* w4 = (const float4*)(Wv + (size_t)o * HDIM);
        float4 a0 = w4[lane], a1 = w4[64+lane], a2 = w4[128+lane], a3 = w4[192+lane];
        float bvo = bv[o], gm = gamma[o], bt = beta[o];
#pragma unroll
        for (int bb = 0; bb < 4; ++bb) {
            float d = dot4(a0, dv[bb][0]) + dot4(a1, dv[bb][1])
                    + dot4(a2, dv[bb][2]) + dot4(a3, dv[bb][3]);
            d = wave_reduce_add(d);
            if (lane == 0) {
                float y = d + bvo;
                out[(b0 + bb) * HDIM + o] = gm * tanhf(al * y) + bt;
            }
        }
    }
}

// ---------------------------------------------------------------------------
extern "C" void kernel_launch(void* const* d_in, const int* in_sizes, int n_in,
                              void* d_out, int out_size, void* d_ws, size_t ws_size,
                              hipStream_t stream) {
    const float* dec   = (const float*)d_in[0];
    const float* enc   = (const float*)d_in[1];
    const float* Wq    = (const float*)d_in[2];
    const float* bq    = (const float*)d_in[3];
    const float* Wk    = (const float*)d_in[4];
    const float* bk    = (const float*)d_in[5];
    const float* Wv    = (const float*)d_in[6];
    const float* bv    = (const float*)d_in[7];
    const float* alpha = (const float*)d_in[8];
    const float* gamma = (const float*)d_in[9];
    const float* beta  = (const float*)d_in[10];
    float* out = (float*)d_out;
    float* ws  = (float*)d_ws;

    hipLaunchKernelGGL(k_q,       dim3(1024), dim3(256), 0, stream, dec, Wq, bq, ws);
    hipLaunchKernelGGL(k_qw,      dim3(2048), dim3(256), 0, stream, Wk, bk, ws);
    hipLaunchKernelGGL(k_flash,   dim3(2048), dim3(256), 0, stream, enc, ws);
    hipLaunchKernelGGL(k_combine, dim3(384),  dim3(256), 0, stream, ws, out);
    hipLaunchKernelGGL(k_out,     dim3(1024), dim3(256), 0, stream, Wv, bv, alpha, gamma, beta, ws, out);
}